// Round 5
// baseline (256.854 us; speedup 1.0000x reference)
//
#include <hip/hip_runtime.h>
#include <math.h>

#define NB 16
#define NS 32
#define NH 768
#define NE 200000
#define NT 200000
#define NR 500
#define NSTEPS 3
#define NWAYS 2

#define HSZ 2048      // frontier hash slots per (gen,b) -- keys shared across ways
#define AHSZ 4096     // accumulator hash slots (final, LDS)
#define BMW 6272      // bitmap u32 words per b (6250 used)
#define PCHUNK 25     // prop chunks per b

typedef unsigned int u32;

__device__ __forceinline__ int fhash(int e) { return (int)(((u32)e * 2654435761u) >> 21); } // 0..2047
__device__ __forceinline__ int ahash(int e) { return (int)(((u32)e * 2654435761u) >> 20); } // 0..4095

// ================= cq partials: disjoint 192x64 stepW slices, b batched =================
// grid: kc(4) x wt(6) x jc(12) = 288 blocks, 256 threads
__global__ __launch_bounds__(256) void cq_part_kernel(
    const float* __restrict__ qe, const float* __restrict__ stepW,
    float* __restrict__ part)
{
    int blk = blockIdx.x;              // kc*72 + wt*12 + jc
    int jc = blk % 12;
    int wt = (blk / 12) % 6;
    int kc = blk / 72;

    __shared__ float s_qe[192 * NB];   // [hh][b]
    __shared__ float s_part[2][1024];

    int tid = threadIdx.x;
    // load qe rows [kc*192, +192) for all b, transposed
    for (int i = tid; i < 192 * NB; i += 256) {
        int b = i / 192, hh = i % 192;
        s_qe[hh * NB + b] = qe[b * NH + kc * 192 + hh];
    }
    __syncthreads();

    int r = tid & 63, p = tid >> 6;
    const float* W = stepW + (size_t)wt * NH * NH + (size_t)(kc * 192) * NH + jc * 64 + r;
    float acc[NB];
#pragma unroll
    for (int b = 0; b < NB; ++b) acc[b] = 0.f;
#pragma unroll 2
    for (int hh = 0; hh < 48; ++hh) {
        int h = p * 48 + hh;
        float w = W[(size_t)h * NH];
        const float4* q4 = (const float4*)&s_qe[h * NB];
        float4 qa = q4[0], qb = q4[1], qc = q4[2], qd = q4[3];
        acc[0]  += w * qa.x; acc[1]  += w * qa.y; acc[2]  += w * qa.z; acc[3]  += w * qa.w;
        acc[4]  += w * qb.x; acc[5]  += w * qb.y; acc[6]  += w * qb.z; acc[7]  += w * qb.w;
        acc[8]  += w * qc.x; acc[9]  += w * qc.y; acc[10] += w * qc.z; acc[11] += w * qc.w;
        acc[12] += w * qd.x; acc[13] += w * qd.y; acc[14] += w * qd.z; acc[15] += w * qd.w;
    }
    if (p >= 2) {
#pragma unroll
        for (int b = 0; b < NB; ++b) s_part[p - 2][b * 64 + r] = acc[b];
    }
    __syncthreads();
    if (p < 2) {
#pragma unroll
        for (int b = 0; b < NB; ++b) s_part[p][b * 64 + r] += acc[b];
    }
    __syncthreads();
    for (int o = tid; o < 1024; o += 256) {
        int b = o >> 6, rr = o & 63;
        part[(((size_t)kc * 6 + wt) * NB + b) * NH + jc * 64 + rr] = s_part[0][o] + s_part[1][o];
    }
}

// ================= attn: reduce cq partials -> tanh -> softmax -> ctx =================
// grid: wt*NB + b (96 blocks)
__global__ __launch_bounds__(256) void attn_kernel(
    const float* __restrict__ part, const float* __restrict__ stepB,
    const float* __restrict__ qwh, const float* __restrict__ mask,
    float* __restrict__ ctx)
{
    int b = blockIdx.x % NB;
    int wt = blockIdx.x / NB;
    __shared__ float s_cq[NH];
    __shared__ float s_sm[NS];
    int tid = threadIdx.x;
    for (int j = tid; j < NH; j += 256) {
        float a = stepB[wt * NH + j];
#pragma unroll
        for (int kc = 0; kc < 4; ++kc)
            a += part[(((size_t)kc * 6 + wt) * NB + b) * NH + j];
        s_cq[j] = tanhf(a);
    }
    __syncthreads();
    {
        int s = tid >> 3, l = tid & 7;
        const float* row = qwh + ((size_t)b * NS + s) * NH;
        float a = 0.f;
        for (int h = l; h < NH; h += 8) a += s_cq[h] * row[h];
        a += __shfl_down(a, 4, 8);
        a += __shfl_down(a, 2, 8);
        a += __shfl_down(a, 1, 8);
        if (l == 0) s_sm[s] = a;
    }
    __syncthreads();
    if (tid == 0) {
        float mx = -1e30f;
        for (int s = 0; s < NS; ++s) mx = fmaxf(mx, s_sm[s]);
        float tmp[NS];
        float sum = 0.f;
        for (int s = 0; s < NS; ++s) { float ev = expf(s_sm[s] - mx); tmp[s] = ev; sum += ev; }
        float inv = 1.f / sum;
        float sum2 = 0.f;
        for (int s = 0; s < NS; ++s) { float d = tmp[s] * inv * mask[b * NS + s]; tmp[s] = d; sum2 += d; }
        float inv2 = 1.f / (sum2 + 1e-6f);
        for (int s = 0; s < NS; ++s) s_sm[s] = tmp[s] * inv2;
    }
    __syncthreads();
    for (int h = tid; h < NH; h += 256) {
        const float* col = qwh + (size_t)b * NS * NH + h;
        float c = 0.f;
#pragma unroll 8
        for (int s = 0; s < NS; ++s) c += s_sm[s] * col[s * NH];
        ctx[((size_t)wt * NB + b) * NH + h] = c;
    }
}

// ================= rel: disjoint relW column slices, b batched =================
// grid: wt(6) x rc(8) = 48 blocks
__global__ __launch_bounds__(256) void rel_kernel(
    const float* __restrict__ ctx, const float* __restrict__ relW,
    const float* __restrict__ relB, float* __restrict__ rel)
{
    int wt = blockIdx.x / 8;
    int rc = blockIdx.x % 8;
    int w = wt / NSTEPS;
    __shared__ float s_ctx[NH * NB];
    __shared__ float s_part[2][1024];
    int tid = threadIdx.x;
    for (int i = tid; i < NB * NH; i += 256) {
        int b = i / NH, h = i % NH;
        s_ctx[h * NB + b] = ctx[(size_t)wt * NB * NH + i];
    }
    __syncthreads();
    int r = tid & 63, p = tid >> 6;
    int col = rc * 64 + r;
    int cl = col < NR ? col : NR - 1;
    const float* W = relW + (size_t)w * NH * NR + cl;
    float acc[NB];
#pragma unroll
    for (int b = 0; b < NB; ++b) acc[b] = 0.f;
    int h1 = p * 192 + 192;
#pragma unroll 2
    for (int h = p * 192; h < h1; ++h) {
        float wv = W[(size_t)h * NR];
        const float4* q4 = (const float4*)&s_ctx[h * NB];
        float4 qa = q4[0], qb = q4[1], qc = q4[2], qd = q4[3];
        acc[0]  += wv * qa.x; acc[1]  += wv * qa.y; acc[2]  += wv * qa.z; acc[3]  += wv * qa.w;
        acc[4]  += wv * qb.x; acc[5]  += wv * qb.y; acc[6]  += wv * qb.z; acc[7]  += wv * qb.w;
        acc[8]  += wv * qc.x; acc[9]  += wv * qc.y; acc[10] += wv * qc.z; acc[11] += wv * qc.w;
        acc[12] += wv * qd.x; acc[13] += wv * qd.y; acc[14] += wv * qd.z; acc[15] += wv * qd.w;
    }
    if (p >= 2) {
#pragma unroll
        for (int b = 0; b < NB; ++b) s_part[p - 2][b * 64 + r] = acc[b];
    }
    __syncthreads();
    if (p < 2) {
#pragma unroll
        for (int b = 0; b < NB; ++b) s_part[p][b * 64 + r] += acc[b];
    }
    __syncthreads();
    for (int o = tid; o < 1024; o += 256) {
        int b = o >> 6, r2 = o & 63;
        int cc = rc * 64 + r2;
        if (cc < NR) {
            float a = s_part[0][o] + s_part[1][o] + relB[w * NR + cc];
            rel[((size_t)wt * NB + b) * NR + cc] = 1.f / (1.f + expf(-a));
        }
    }
}

// ================= hop attention =================
__global__ __launch_bounds__(192) void hop_kernel(
    const float* __restrict__ qe, const float* __restrict__ hopW,
    const float* __restrict__ hopB, float* __restrict__ hop)
{
    int wb = blockIdx.x;
    int w = wb / NB, b = wb % NB;
    int t = threadIdx.x / 64, l = threadIdx.x % 64;
    __shared__ float s_logit[4];
    float a = 0.f;
    for (int h = l; h < NH; h += 64) a += qe[b * NH + h] * hopW[((size_t)w * NH + h) * NSTEPS + t];
    for (int off = 32; off; off >>= 1) a += __shfl_down(a, off, 64);
    if (l == 0) s_logit[t] = a + hopB[w * NSTEPS + t];
    __syncthreads();
    if (threadIdx.x == 0) {
        float mx = fmaxf(s_logit[0], fmaxf(s_logit[1], s_logit[2]));
        float e0 = expf(s_logit[0] - mx), e1 = expf(s_logit[1] - mx), e2 = expf(s_logit[2] - mx);
        float inv = 1.f / (e0 + e1 + e2);
        hop[wb * NSTEPS + 0] = e0 * inv;
        hop[wb * NSTEPS + 1] = e1 * inv;
        hop[wb * NSTEPS + 2] = e2 * inv;
    }
}

// ================= gen0 frontier from one-hot heads =================
__global__ void head_kernel(const float* __restrict__ heads, int* __restrict__ keys0,
                            float* __restrict__ vals0, u32* __restrict__ bm0)
{
    size_t N4 = (size_t)NB * NE / 4;
    const float4* h4 = (const float4*)heads;
    for (size_t i = (size_t)blockIdx.x * blockDim.x + threadIdx.x; i < N4;
         i += (size_t)gridDim.x * blockDim.x) {
        float4 v = h4[i];
        float c[4] = { v.x, v.y, v.z, v.w };
#pragma unroll
        for (int k = 0; k < 4; ++k) {
            if (c[k] != 0.0f) {
                size_t idx = i * 4 + k;
                int b = (int)(idx / NE);
                int e = (int)(idx % NE);
                int s = fhash(e);
                keys0[(size_t)b * HSZ + s] = e + 1;
                vals0[(size_t)b * HSZ + s] = 1.0f;
                vals0[(size_t)(NB + b) * HSZ + s] = 1.0f;
                atomicOr(&bm0[(size_t)b * BMW + (e >> 5)], 1u << (e & 31));
            }
        }
    }
}

// ================= propagate gen t -> gen t+1 (both ways, shared keys) =================
// grid: b(16) x chunk(25) = 400 blocks
__global__ __launch_bounds__(256) void prop_kernel(
    const int* __restrict__ triples,
    const u32* __restrict__ bmIn, const int* __restrict__ keysIn, const float* __restrict__ valsIn,
    u32* __restrict__ bmOut, int* __restrict__ keysOut, float* __restrict__ valsOut,
    const float* __restrict__ rel, int t)
{
    __shared__ u32 s_bm[BMW];
    int b = blockIdx.x / PCHUNK;
    int c = blockIdx.x % PCHUNK;
    const u32* g = bmIn + (size_t)b * BMW;
    for (int k = threadIdx.x; k < BMW; k += 256) s_bm[k] = g[k];
    __syncthreads();

    const int*   kin  = keysIn  + (size_t)b * HSZ;
    const float* v0in = valsIn  + (size_t)b * HSZ;
    const float* v1in = valsIn  + (size_t)(NB + b) * HSZ;
    const float* r0 = rel + ((size_t)(0 * NSTEPS + t) * NB + b) * NR;
    const float* r1 = rel + ((size_t)(1 * NSTEPS + t) * NB + b) * NR;
    int*   kout  = keysOut + (size_t)b * HSZ;
    float* v0out = valsOut + (size_t)b * HSZ;
    float* v1out = valsOut + (size_t)(NB + b) * HSZ;
    u32*   bmo   = bmOut + (size_t)b * BMW;

    const int4* tp = (const int4*)(triples + (size_t)b * NT * 3);
    const int QPC = (NT / 4) / PCHUNK;     // 2000 quads per chunk
    int qend = (c + 1) * QPC;
    for (int q = c * QPC + threadIdx.x; q < qend; q += 256) {
        int4 x = tp[q * 3 + 0];
        int4 y = tp[q * 3 + 1];
        int4 z = tp[q * 3 + 2];
        int su[4] = { x.x, x.w, y.z, z.y };
        int re[4] = { x.y, y.x, y.w, z.z };
        int ob[4] = { x.z, y.y, z.x, z.w };
#pragma unroll
        for (int k = 0; k < 4; ++k) {
            int sub = su[k];
            if ((s_bm[sub >> 5] >> (sub & 31)) & 1u) {
                int s = fhash(sub);
                float v0 = 0.f, v1 = 0.f;
                bool found = false;
                for (int p = 0; p < HSZ; ++p) {
                    int kk = kin[s];
                    if (kk == 0) break;
                    if (kk == sub + 1) {
                        v0 = fminf(v0in[s], 1.0f);
                        v1 = fminf(v1in[s], 1.0f);
                        found = true;
                        break;
                    }
                    s = (s + 1) & (HSZ - 1);
                }
                if (found) {
                    float c0 = v0 * r0[re[k]];
                    float c1 = v1 * r1[re[k]];
                    int e = ob[k];
                    int s2 = fhash(e);
                    for (int p = 0; p < HSZ; ++p) {
                        int old = atomicCAS(&kout[s2], 0, e + 1);
                        if (old == 0 || old == e + 1) {
                            atomicAdd(&v0out[s2], c0);
                            atomicAdd(&v1out[s2], c1);
                            if (old == 0) atomicOr(&bmo[e >> 5], 1u << (e & 31));
                            break;
                        }
                        s2 = (s2 + 1) & (HSZ - 1);
                    }
                }
            }
        }
    }
}

// ================= final: hop-weighted accumulate gens 1..3, product of ways =================
__global__ __launch_bounds__(256) void final_kernel(
    const int* __restrict__ keysG, const float* __restrict__ valsG,
    const float* __restrict__ hop, float* __restrict__ out)
{
    __shared__ int s_k[AHSZ];
    __shared__ float s_v0[AHSZ];
    __shared__ float s_v1[AHSZ];
    int b = blockIdx.x;
    for (int i = threadIdx.x; i < AHSZ; i += 256) { s_k[i] = 0; s_v0[i] = 0.f; s_v1[i] = 0.f; }
    __syncthreads();
    for (int gen = 1; gen <= 3; ++gen) {
        const int* kg = keysG + ((size_t)gen * NB + b) * HSZ;
        const float* vg = valsG + (size_t)gen * NWAYS * NB * HSZ;
        const float* v0 = vg + (size_t)b * HSZ;
        const float* v1 = vg + (size_t)(NB + b) * HSZ;
        float h0 = hop[(0 * NB + b) * NSTEPS + (gen - 1)];
        float h1 = hop[(1 * NB + b) * NSTEPS + (gen - 1)];
        for (int i = threadIdx.x; i < HSZ; i += 256) {
            int key = kg[i];
            if (key == 0) continue;
            float a0 = h0 * fminf(v0[i], 1.0f);
            float a1 = h1 * fminf(v1[i], 1.0f);
            int s = ahash(key - 1);
            for (int p = 0; p < AHSZ; ++p) {
                int old = atomicCAS(&s_k[s], 0, key);
                if (old == 0 || old == key) {
                    atomicAdd(&s_v0[s], a0);
                    atomicAdd(&s_v1[s], a1);
                    break;
                }
                s = (s + 1) & (AHSZ - 1);
            }
        }
    }
    __syncthreads();
    for (int i = threadIdx.x; i < AHSZ; i += 256) {
        int key = s_k[i];
        if (key) out[(size_t)b * NE + (key - 1)] = s_v0[i] * s_v1[i];
    }
}

extern "C" void kernel_launch(void* const* d_in, const int* in_sizes, int n_in,
                              void* d_out, int out_size, void* d_ws, size_t ws_size,
                              hipStream_t stream)
{
    const float* heads  = (const float*)d_in[0];
    const float* qe     = (const float*)d_in[1];
    const float* qwh    = (const float*)d_in[2];
    const float* mask   = (const float*)d_in[3];
    const float* stepW  = (const float*)d_in[4];
    const float* stepB  = (const float*)d_in[5];
    const float* relW   = (const float*)d_in[6];
    const float* relB   = (const float*)d_in[7];
    const float* hopW   = (const float*)d_in[8];
    const float* hopB   = (const float*)d_in[9];
    const int*   triples = (const int*)d_in[10];
    float* out = (float*)d_out;

    // workspace: [keysG 4][valsG 4x2][bmG 4][rel][hop][part][ctx]
    int*   keysG = (int*)d_ws;                                   // 4*16*2048
    float* valsG = (float*)(keysG + 4 * NB * HSZ);               // 4*2*16*2048
    u32*   bmG   = (u32*)(valsG + 4 * NWAYS * NB * HSZ);         // 4*16*6272
    float* rel   = (float*)(bmG + 4 * (size_t)NB * BMW);         // 96*500
    float* hop   = rel + (size_t)NWAYS * NSTEPS * NB * NR;       // 96
    float* part  = hop + NWAYS * NB * NSTEPS;                    // 4*6*16*768
    float* ctx   = part + (size_t)4 * 6 * NB * NH;               // 6*16*768

    size_t zero_bytes = (char*)rel - (char*)d_ws;                // keys+vals+bm, ~3.1 MB
    hipMemsetAsync(d_ws, 0, zero_bytes, stream);
    hipMemsetAsync(d_out, 0, (size_t)NB * NE * sizeof(float), stream);

    cq_part_kernel<<<288, 256, 0, stream>>>(qe, stepW, part);
    attn_kernel<<<96, 256, 0, stream>>>(part, stepB, qwh, mask, ctx);
    rel_kernel<<<48, 256, 0, stream>>>(ctx, relW, relB, rel);
    hop_kernel<<<NWAYS * NB, 192, 0, stream>>>(qe, hopW, hopB, hop);
    head_kernel<<<2048, 256, 0, stream>>>(heads, keysG, valsG, bmG);

    for (int t = 0; t < NSTEPS; ++t) {
        prop_kernel<<<NB * PCHUNK, 256, 0, stream>>>(
            triples,
            bmG + (size_t)t * NB * BMW,
            keysG + (size_t)t * NB * HSZ,
            valsG + (size_t)t * NWAYS * NB * HSZ,
            bmG + (size_t)(t + 1) * NB * BMW,
            keysG + (size_t)(t + 1) * NB * HSZ,
            valsG + (size_t)(t + 1) * NWAYS * NB * HSZ,
            rel, t);
    }

    final_kernel<<<NB, 256, 0, stream>>>(keysG, valsG, hop, out);
}